// Round 2
// baseline (1772.277 us; speedup 1.0000x reference)
//
#include <hip/hip_runtime.h>
#include <stdint.h>

#define NN 8192
#define DD 128
#define ALPHA 0.7f
#define BETA 0.3f
#define LAM 0.1f
#define QSCALE 0.08838834764831845f  // 1/sqrt(128)
#define DELTA 3e-5f
#define FLAGCAP 262144

typedef __attribute__((ext_vector_type(8))) short short8;
typedef __attribute__((ext_vector_type(4))) float f32x4;

__device__ __forceinline__ unsigned short f2bf(float f){
  union { float f; unsigned u; } v; v.f = f;
  return (unsigned short)((v.u + 0x7FFFu + ((v.u >> 16) & 1u)) >> 16);
}
__device__ __forceinline__ float bf2f(unsigned short s){
  union { unsigned u; float f; } v; v.u = ((unsigned)s) << 16; return v.f;
}

// ---------------- adjacency -> bitmask ----------------
__global__ void k_pack(const float* __restrict__ adj, unsigned* __restrict__ adjw){
  int i = blockIdx.x, wave = threadIdx.x >> 6, lane = threadIdx.x & 63;
  for (int seg = wave; seg < 128; seg += 4){
    int j = seg*64 + lane;
    unsigned long long bm = __ballot(adj[(size_t)i*NN + j] != 0.0f);
    if (lane == 0)  adjw[i*256 + seg*2]     = (unsigned)bm;
    if (lane == 32) adjw[i*256 + seg*2 + 1] = (unsigned)(bm >> 32);
  }
}

// ---------------- norms + hi/lo split ----------------
__global__ void k_norm(const float* __restrict__ E, float* __restrict__ invn,
                       double* __restrict__ nrm64,
                       unsigned short* __restrict__ Ehi, unsigned short* __restrict__ Elo){
  int i = blockIdx.x, l = threadIdx.x;
  float v0 = E[i*DD + l], v1 = E[i*DD + 64 + l];
  double ss = (double)v0*(double)v0 + (double)v1*(double)v1;
  #pragma unroll
  for (int m = 32; m; m >>= 1) ss += __shfl_xor(ss, m, 64);
  double nr = sqrt(ss); if (nr < 1e-8) nr = 1e-8;
  unsigned short h0 = f2bf(v0), h1 = f2bf(v1);
  Ehi[i*DD + l] = h0;       Ehi[i*DD + 64 + l] = h1;
  Elo[i*DD + l] = f2bf(v0 - bf2f(h0));
  Elo[i*DD + 64 + l] = f2bf(v1 - bf2f(h1));
  if (l == 0){ invn[i] = (float)(1.0 / nr); nrm64[i] = nr; }
}

// ---------------- bf16 transpose [8192,128] -> [128,8192] ----------------
__global__ void k_transpose(const unsigned short* __restrict__ in, unsigned short* __restrict__ out){
  __shared__ unsigned short t[64][65];
  int r0 = blockIdx.x * 64, c0 = blockIdx.y * 64;
  for (int idx = threadIdx.x; idx < 4096; idx += 256){
    int r = idx >> 6, c = idx & 63;
    t[r][c] = in[(r0 + r)*DD + c0 + c];
  }
  __syncthreads();
  for (int idx = threadIdx.x; idx < 4096; idx += 256){
    int c = idx >> 6, r = idx & 63;
    out[(size_t)(c0 + c)*NN + r0 + r] = t[r][c];
  }
}

// ---------------- fp32 weight transpose+split [K,N] -> hi/lo bf16 [N,K] ----------------
__global__ void k_transw(const float* __restrict__ in, unsigned short* __restrict__ outH,
                         unsigned short* __restrict__ outL, int K, int Nout){
  int idx = blockIdx.x * blockDim.x + threadIdx.x;
  if (idx < K * Nout){
    int k = idx / Nout, n = idx - k*Nout;
    float v = in[idx];
    unsigned short h = f2bf(v);
    outH[n*K + k] = h;
    outL[n*K + k] = f2bf(v - bf2f(h));
  }
}

// ---------------- hi/lo MFMA GEMM: out = act((A@W + b) * scale) ----------------
// A: 4 row-major [M,128] fp32 slices (virtual concat along K). BtH/BtL: W^T split bf16 [NOUT,K].
// OMODE: 0 = fp32 out, 1 = bf16 hi out, 2 = bf16 hi+lo out
template<int KSTEPS, int NOUT, bool RELU, int OMODE>
__global__ void k_gemm(const float* __restrict__ A0, const float* __restrict__ A1,
                       const float* __restrict__ A2, const float* __restrict__ A3,
                       const unsigned short* __restrict__ BtH, const unsigned short* __restrict__ BtL,
                       const float* __restrict__ bias, float scale,
                       float* __restrict__ outF, unsigned short* __restrict__ outH,
                       unsigned short* __restrict__ outL){
  const int K = KSTEPS * 32;
  int lane = threadIdx.x & 63, wave = threadIdx.x >> 6;
  int l15 = lane & 15, quad = lane >> 4;
  int row16 = blockIdx.x * 32 + wave * 16;
  const float* bases[4] = {A0, A1, A2, A3};
  f32x4 acc[NOUT/16];
  #pragma unroll
  for (int nf = 0; nf < NOUT/16; nf++){ f32x4 z = {0.f,0.f,0.f,0.f}; acc[nf] = z; }
  #pragma unroll
  for (int kk = 0; kk < KSTEPS; kk++){
    const float* Ab = bases[kk >> 2];
    int koff = (kk & 3)*32 + quad*8;
    const float* ap = &Ab[(row16 + l15)*DD + koff];
    short8 ah, al;
    #pragma unroll
    for (int j = 0; j < 8; j++){
      float v = ap[j];
      unsigned short h = f2bf(v);
      ah[j] = (short)h; al[j] = (short)f2bf(v - bf2f(h));
    }
    #pragma unroll
    for (int nf = 0; nf < NOUT/16; nf++){
      int bo = (nf*16 + l15)*K + kk*32 + quad*8;
      short8 bh = *(const short8*)&BtH[bo];
      short8 bl = *(const short8*)&BtL[bo];
      acc[nf] = __builtin_amdgcn_mfma_f32_16x16x32_bf16(ah, bh, acc[nf], 0, 0, 0);
      acc[nf] = __builtin_amdgcn_mfma_f32_16x16x32_bf16(al, bh, acc[nf], 0, 0, 0);
      acc[nf] = __builtin_amdgcn_mfma_f32_16x16x32_bf16(ah, bl, acc[nf], 0, 0, 0);
    }
  }
  #pragma unroll
  for (int nf = 0; nf < NOUT/16; nf++){
    int col = nf*16 + l15;
    float b = bias[col];
    #pragma unroll
    for (int r = 0; r < 4; r++){
      int row = row16 + quad*4 + r;
      float v = (acc[nf][r] + b) * scale;
      if (RELU) v = fmaxf(v, 0.f);
      if (OMODE == 0) outF[row*NOUT + col] = v;
      else {
        unsigned short h = f2bf(v);
        outH[row*NOUT + col] = h;
        if (OMODE == 2) outL[row*NOUT + col] = f2bf(v - bf2f(h));
      }
    }
  }
}

// ---------------- fused sim/classify/aggregate ----------------
#define BM 64
#define BN 32
#define CSPLIT 4
#define CCHUNK (NN/CSPLIT)
#define NTILES (CCHUNK/BN)

__launch_bounds__(256, 2)
__global__ void k_fused(const unsigned* __restrict__ adjw, const float* __restrict__ invn,
    const unsigned short* __restrict__ Ehi, const unsigned short* __restrict__ Elo,
    const unsigned short* __restrict__ EhiT, const unsigned short* __restrict__ EloT,
    const unsigned short* __restrict__ Qh,  const unsigned short* __restrict__ Kh,
    const unsigned short* __restrict__ VhT, const unsigned short* __restrict__ VloT,
    float* __restrict__ Psum, float* __restrict__ Nsum, float* __restrict__ Bsum,
    float* __restrict__ cntP, float* __restrict__ cntN, float* __restrict__ denB,
    int* __restrict__ flagCnt, float4* __restrict__ flags)
{
  __shared__ __attribute__((aligned(16))) unsigned short sEhi[BN*DD];
  __shared__ __attribute__((aligned(16))) unsigned short sElo[BN*DD];
  __shared__ __attribute__((aligned(16))) unsigned short sKh [BN*DD];
  __shared__ __attribute__((aligned(16))) unsigned short sEt  [DD*BN];  // EhiT feature-major
  __shared__ __attribute__((aligned(16))) unsigned short sEtl [DD*BN];  // EloT
  __shared__ __attribute__((aligned(16))) unsigned short sVt  [DD*BN];  // VhT
  __shared__ __attribute__((aligned(16))) unsigned short sVtl [DD*BN];  // VloT
  __shared__ __attribute__((aligned(16))) unsigned short sMask[4][4][16*BN]; // pos,neg,ehi,elo
  int tid = threadIdx.x, lane = tid & 63, wave = tid >> 6;
  int l15 = lane & 15, quad = lane >> 4;
  int rowblk = blockIdx.x >> 2, split = blockIdx.x & 3;
  int row0 = rowblk * BM + wave * 16;
  int col0 = split * CCHUNK;

  short8 aEh[4], aEl[4], aQ[4];
  #pragma unroll
  for (int kf = 0; kf < 4; kf++){
    int go = (row0 + l15)*DD + kf*32 + quad*8;
    aEh[kf] = *(const short8*)&Ehi[go];
    aEl[kf] = *(const short8*)&Elo[go];
    aQ [kf] = *(const short8*)&Qh [go];
  }
  float invr[4];
  #pragma unroll
  for (int r = 0; r < 4; r++) invr[r] = invn[row0 + quad*4 + r];

  f32x4 accP[8], accN[8], accB[8];
  #pragma unroll
  for (int nf = 0; nf < 8; nf++){ f32x4 z = {0.f,0.f,0.f,0.f}; accP[nf]=z; accN[nf]=z; accB[nf]=z; }
  float cp[4] = {0,0,0,0}, cn[4] = {0,0,0,0}, db[4] = {0,0,0,0};

  for (int t = 0; t < NTILES; t++){
    int c0 = col0 + t*BN;
    __syncthreads();
    #pragma unroll
    for (int rep = 0; rep < 2; rep++){
      int id = tid + rep*256;
      int row = id >> 4, off = (id & 15)*8;
      int g = (c0 + row)*DD + off;
      *(uint4*)&sEhi[row*DD + off] = *(const uint4*)&Ehi[g];
      *(uint4*)&sElo[row*DD + off] = *(const uint4*)&Elo[g];
      *(uint4*)&sKh [row*DD + off] = *(const uint4*)&Kh [g];
      int fr = id >> 2, no = (id & 3)*8;
      size_t gt = (size_t)fr*NN + c0 + no;
      *(uint4*)&sEt [fr*BN + no] = *(const uint4*)&EhiT[gt];
      *(uint4*)&sEtl[fr*BN + no] = *(const uint4*)&EloT[gt];
      *(uint4*)&sVt [fr*BN + no] = *(const uint4*)&VhT [gt];
      *(uint4*)&sVtl[fr*BN + no] = *(const uint4*)&VloT[gt];
    }
    __syncthreads();

    f32x4 sim[2], sv[2];
    { f32x4 z = {0.f,0.f,0.f,0.f}; sim[0]=z; sim[1]=z; sv[0]=z; sv[1]=z; }
    #pragma unroll
    for (int f = 0; f < 2; f++){
      #pragma unroll
      for (int kf = 0; kf < 4; kf++){
        int la = (f*16 + l15)*DD + kf*32 + quad*8;
        short8 bh = *(const short8*)&sEhi[la];
        short8 bl = *(const short8*)&sElo[la];
        short8 bk = *(const short8*)&sKh [la];
        sim[f] = __builtin_amdgcn_mfma_f32_16x16x32_bf16(aEh[kf], bh, sim[f],0,0,0);
        sim[f] = __builtin_amdgcn_mfma_f32_16x16x32_bf16(aEl[kf], bh, sim[f],0,0,0);
        sim[f] = __builtin_amdgcn_mfma_f32_16x16x32_bf16(aEh[kf], bl, sim[f],0,0,0);
        sv[f]  = __builtin_amdgcn_mfma_f32_16x16x32_bf16(aQ [kf], bk, sv[f],0,0,0);
      }
    }
    // classify
    int cw = c0 >> 5;
    #pragma unroll
    for (int f = 0; f < 2; f++){
      int jg = c0 + f*16 + l15;
      float invc = invn[jg];
      int bitidx = f*16 + l15;
      #pragma unroll
      for (int r = 0; r < 4; r++){
        int ig = row0 + quad*4 + r;
        unsigned aw = adjw[ig*256 + cw];
        bool nbr = (aw >> bitidx) & 1u;
        float c = sim[f][r] * invr[r] * invc;
        float s = sv[f][r];
        bool pos = nbr && (c >= ALPHA);
        bool neg = nbr && (c <= BETA);
        bool bnd = nbr && !pos && !neg;
        float e = bnd ? __expf(s) : 0.f;
        unsigned short eh = f2bf(e);
        int mo = (quad*4 + r)*BN + f*16 + l15;
        sMask[wave][0][mo] = pos ? (unsigned short)0x3F80 : (unsigned short)0;
        sMask[wave][1][mo] = neg ? (unsigned short)0x3F80 : (unsigned short)0;
        sMask[wave][2][mo] = eh;
        sMask[wave][3][mo] = f2bf(e - bf2f(eh));
        cp[r] += pos ? 1.f : 0.f;
        cn[r] += neg ? 1.f : 0.f;
        db[r] += e;
        bool flag = nbr && (fabsf(c - ALPHA) < DELTA || fabsf(c - BETA) < DELTA);
        unsigned long long bm = __ballot(flag);
        if (bm){
          int leader = __ffsll((long long)bm) - 1;
          int base = 0;
          if (lane == leader) base = atomicAdd(flagCnt, __popcll(bm));
          base = __shfl(base, leader, 64);
          if (flag){
            int id = base + __popcll(bm & ((1ull << lane) - 1ull));
            if (id < FLAGCAP){
              float4 rec; rec.x = __int_as_float(ig); rec.y = __int_as_float(jg);
              rec.z = c; rec.w = s;
              flags[id] = rec;
            }
          }
        }
      }
    }
    // masked accumulations (same-wave LDS RAW; DS pipeline is in-order per wave)
    short8 mPos = *(const short8*)&sMask[wave][0][l15*BN + quad*8];
    short8 mNeg = *(const short8*)&sMask[wave][1][l15*BN + quad*8];
    short8 mEh  = *(const short8*)&sMask[wave][2][l15*BN + quad*8];
    short8 mEl  = *(const short8*)&sMask[wave][3][l15*BN + quad*8];
    #pragma unroll
    for (int nf = 0; nf < 8; nf++){
      int so = (nf*16 + l15)*BN + quad*8;
      short8 et = *(const short8*)&sEt [so];
      short8 el = *(const short8*)&sEtl[so];
      short8 vt = *(const short8*)&sVt [so];
      short8 vl = *(const short8*)&sVtl[so];
      accP[nf] = __builtin_amdgcn_mfma_f32_16x16x32_bf16(mPos, et, accP[nf],0,0,0);
      accP[nf] = __builtin_amdgcn_mfma_f32_16x16x32_bf16(mPos, el, accP[nf],0,0,0);
      accN[nf] = __builtin_amdgcn_mfma_f32_16x16x32_bf16(mNeg, et, accN[nf],0,0,0);
      accN[nf] = __builtin_amdgcn_mfma_f32_16x16x32_bf16(mNeg, el, accN[nf],0,0,0);
      accB[nf] = __builtin_amdgcn_mfma_f32_16x16x32_bf16(mEh,  vt, accB[nf],0,0,0);
      accB[nf] = __builtin_amdgcn_mfma_f32_16x16x32_bf16(mEl,  vt, accB[nf],0,0,0);
      accB[nf] = __builtin_amdgcn_mfma_f32_16x16x32_bf16(mEh,  vl, accB[nf],0,0,0);
    }
  }
  // writeback
  #pragma unroll
  for (int nf = 0; nf < 8; nf++){
    int col = nf*16 + l15;
    #pragma unroll
    for (int r = 0; r < 4; r++){
      int row = row0 + quad*4 + r;
      atomicAdd(&Psum[row*DD + col], accP[nf][r]);
      atomicAdd(&Nsum[row*DD + col], accN[nf][r]);
      atomicAdd(&Bsum[row*DD + col], accB[nf][r]);
    }
  }
  #pragma unroll
  for (int r = 0; r < 4; r++){
    float vp = cp[r], vn = cn[r], vb = db[r];
    #pragma unroll
    for (int m = 1; m < 16; m <<= 1){
      vp += __shfl_xor(vp, m, 64);
      vn += __shfl_xor(vn, m, 64);
      vb += __shfl_xor(vb, m, 64);
    }
    if (l15 == 0){
      int row = row0 + quad*4 + r;
      atomicAdd(&cntP[row], vp);
      atomicAdd(&cntN[row], vn);
      atomicAdd(&denB[row], vb);
    }
  }
}

// ---------------- fp64 boundary refinement + sparse fixup ----------------
__global__ void k_refine(const float* __restrict__ E, const double* __restrict__ nrm64,
    const unsigned short* __restrict__ Ehi, const unsigned short* __restrict__ Elo,
    const unsigned short* __restrict__ VhT, const unsigned short* __restrict__ VloT,
    const int* __restrict__ flagCnt, const float4* __restrict__ flags,
    float* __restrict__ Psum, float* __restrict__ Nsum, float* __restrict__ Bsum,
    float* __restrict__ cntP, float* __restrict__ cntN, float* __restrict__ denB)
{
  int cnt = *flagCnt; if (cnt > FLAGCAP) cnt = FLAGCAP;
  int lane = threadIdx.x & 63;
  int gw = (blockIdx.x * blockDim.x + threadIdx.x) >> 6;
  int nw = (gridDim.x * blockDim.x) >> 6;
  for (int idx = gw; idx < cnt; idx += nw){
    float4 rec = flags[idx];
    int i = __float_as_int(rec.x), j = __float_as_int(rec.y);
    float c = rec.z, s = rec.w;
    float ei0 = E[i*DD + lane], ei1 = E[i*DD + 64 + lane];
    float ej0 = E[j*DD + lane], ej1 = E[j*DD + 64 + lane];
    double d = (double)ei0*(double)ej0 + (double)ei1*(double)ej1;
    #pragma unroll
    for (int m = 32; m; m >>= 1) d += __shfl_xor(d, m, 64);
    double se = d / (nrm64[i]*nrm64[j]);
    int ce = (se >= (double)ALPHA) ? 0 : ((se <= (double)BETA) ? 1 : 2);
    int cc = (c >= ALPHA) ? 0 : ((c <= BETA) ? 1 : 2);
    if (ce == cc) continue;
    float e = __expf(s);
    float ehf = bf2f(f2bf(e));
    float elf = bf2f(f2bf(e - ehf));
    #pragma unroll
    for (int h = 0; h < 2; h++){
      int dd2 = lane + h*64;
      float ev = bf2f(Ehi[j*DD + dd2]) + bf2f(Elo[j*DD + dd2]);
      float vh = bf2f(VhT[(size_t)dd2*NN + j]);
      float vl = bf2f(VloT[(size_t)dd2*NN + j]);
      float bv = ehf*vh + elf*vh + ehf*vl;
      float* subA = (cc==0) ? Psum : (cc==1) ? Nsum : Bsum;
      atomicAdd(&subA[i*DD + dd2], (cc==2) ? -bv : -ev);
      float* addA = (ce==0) ? Psum : (ce==1) ? Nsum : Bsum;
      atomicAdd(&addA[i*DD + dd2], (ce==2) ?  bv :  ev);
    }
    if (lane == 0){
      float* subC = (cc==0) ? cntP : (cc==1) ? cntN : denB;
      atomicAdd(&subC[i], (cc==2) ? -e : -1.f);
      float* addC = (ce==0) ? cntP : (ce==1) ? cntN : denB;
      atomicAdd(&addC[i], (ce==2) ?  e :  1.f);
    }
  }
}

// ---------------- divide sums into region embeddings (in place) ----------------
__global__ void k_regions(float* __restrict__ P, float* __restrict__ Nn, float* __restrict__ B,
    const float* __restrict__ cntP, const float* __restrict__ cntN, const float* __restrict__ denB){
  int idx = blockIdx.x*blockDim.x + threadIdx.x;
  int i = idx >> 7;
  P[idx]  = P[idx] / fmaxf(cntP[i], 1.f);
  Nn[idx] = LAM * Nn[idx] / fmaxf(cntN[i], 1.f);
  float dn = denB[i];
  B[idx]  = (dn > 0.5f) ? B[idx]/dn : 0.f;   // nonempty denom is >= exp(-0.01)*n >= ~0.99
}

// ---------------- gate + fuse ----------------
__global__ void k_fuse(const float* __restrict__ E, const float* __restrict__ P,
    const float* __restrict__ B, const float* __restrict__ Nn,
    const float* __restrict__ h, const float* __restrict__ g2w, const float* __restrict__ g2b,
    const float* __restrict__ cntP, const float* __restrict__ cntN, const float* __restrict__ denB,
    float* __restrict__ agg){
  int i = blockIdx.x, lane = threadIdx.x;
  float l0=0,l1=0,l2=0,l3=0;
  #pragma unroll
  for (int kk = 0; kk < 4; kk++){
    int k = lane + kk*64;
    float hv = h[i*256 + k];
    l0 = fmaf(hv, g2w[k*4+0], l0);
    l1 = fmaf(hv, g2w[k*4+1], l1);
    l2 = fmaf(hv, g2w[k*4+2], l2);
    l3 = fmaf(hv, g2w[k*4+3], l3);
  }
  #pragma unroll
  for (int m = 1; m < 64; m <<= 1){
    l0 += __shfl_xor(l0, m, 64); l1 += __shfl_xor(l1, m, 64);
    l2 += __shfl_xor(l2, m, 64); l3 += __shfl_xor(l3, m, 64);
  }
  l0 += g2b[0]; l1 += g2b[1]; l2 += g2b[2]; l3 += g2b[3];
  float mx = fmaxf(fmaxf(l0,l1), fmaxf(l2,l3));
  float e0 = __expf(l0-mx), e1 = __expf(l1-mx), e2 = __expf(l2-mx), e3 = __expf(l3-mx);
  float inv = 1.f/(e0+e1+e2+e3);
  float g0 = e0*inv, g1 = e1*inv, g2v = e2*inv, g3 = e3*inv;
  bool any = (cntP[i] + cntN[i] > 0.5f) || (denB[i] > 0.5f);
  #pragma unroll
  for (int hh = 0; hh < 2; hh++){
    int idx = i*DD + lane + hh*64;
    float v = any ? (g0*E[idx] + g1*P[idx] + g2v*B[idx] + g3*Nn[idx]) : E[idx];
    agg[idx] = v;
  }
}

// ---------------- final layer-weighted combine ----------------
__global__ void k_final(const float* __restrict__ c0, const float* __restrict__ c1,
                        const float* __restrict__ lwv, float* __restrict__ out){
  int idx = blockIdx.x*blockDim.x + threadIdx.x;
  float w0 = lwv[0], w1 = lwv[1];
  float mx = fmaxf(w0, w1);
  float e0 = __expf(w0-mx), e1 = __expf(w1-mx);
  float inv = 1.f/(e0+e1);
  out[idx] = (e0*inv)*c0[idx] + (e1*inv)*c1[idx];
}

extern "C" void kernel_launch(void* const* d_in, const int* in_sizes, int n_in,
                              void* d_out, int out_size, void* d_ws, size_t ws_size,
                              hipStream_t stream){
  const float* adj   = (const float*)d_in[0];
  const float* embed = (const float*)d_in[1];
  const float* gc_w  = (const float*)d_in[2];
  const float* gc_b  = (const float*)d_in[3];
  const float* wq = (const float*)d_in[4];
  const float* bq = (const float*)d_in[5];
  const float* wk = (const float*)d_in[6];
  const float* bk = (const float*)d_in[7];
  const float* wv = (const float*)d_in[8];
  const float* bv = (const float*)d_in[9];
  const float* g1w = (const float*)d_in[10];
  const float* g1b = (const float*)d_in[11];
  const float* g2w = (const float*)d_in[12];
  const float* g2b = (const float*)d_in[13];
  const float* lw  = (const float*)d_in[14];
  float* out = (float*)d_out;

  char* p = (char*)d_ws;
  auto alloc = [&](size_t bytes)->void*{ void* r = (void*)p; p += (bytes + 255) & ~(size_t)255; return r; };
  typedef unsigned short ush;
  ush* wqTh  = (ush*)alloc(128*128*2); ush* wqTl  = (ush*)alloc(128*128*2);
  ush* wkTh  = (ush*)alloc(128*128*2); ush* wkTl  = (ush*)alloc(128*128*2);
  ush* wvTh  = (ush*)alloc(128*128*2); ush* wvTl  = (ush*)alloc(128*128*2);
  ush* g1wTh = (ush*)alloc(512*256*2); ush* g1wTl = (ush*)alloc(512*256*2);
  ush* gcwTh = (ush*)alloc(2*128*128*2); ush* gcwTl = (ush*)alloc(2*128*128*2);
  unsigned* adjw = (unsigned*)alloc((size_t)NN*256*4);
  float* invn   = (float*)alloc(NN*4);
  double* nrm64 = (double*)alloc(NN*8);
  ush* Ehi  = (ush*)alloc((size_t)NN*DD*2);
  ush* Elo  = (ush*)alloc((size_t)NN*DD*2);
  ush* EhiT = (ush*)alloc((size_t)NN*DD*2);
  ush* EloT = (ush*)alloc((size_t)NN*DD*2);
  ush* Qh   = (ush*)alloc((size_t)NN*DD*2);
  ush* Khb  = (ush*)alloc((size_t)NN*DD*2);
  ush* Vh   = (ush*)alloc((size_t)NN*DD*2);
  ush* Vlo  = (ush*)alloc((size_t)NN*DD*2);
  ush* VhT  = (ush*)alloc((size_t)NN*DD*2);
  ush* VloT = (ush*)alloc((size_t)NN*DD*2);
  char* zbase = p;
  float* Psum = (float*)alloc((size_t)NN*DD*4);
  float* Nsum = (float*)alloc((size_t)NN*DD*4);
  float* Bsum = (float*)alloc((size_t)NN*DD*4);
  float* cntP = (float*)alloc(NN*4);
  float* cntN = (float*)alloc(NN*4);
  float* denB = (float*)alloc(NN*4);
  int*   flagCnt = (int*)alloc(256);
  size_t zbytes = (size_t)(p - zbase);
  float4* flags = (float4*)alloc((size_t)FLAGCAP*16);
  float* hbuf = (float*)alloc((size_t)NN*256*4);
  float* aggb = (float*)alloc((size_t)NN*DD*4);
  float* cur0 = (float*)alloc((size_t)NN*DD*4);
  float* cur1 = (float*)alloc((size_t)NN*DD*4);

  // one-time prep (per call; inputs restored each replay)
  k_pack<<<NN, 256, 0, stream>>>(adj, adjw);
  k_transw<<<(128*128+255)/256, 256, 0, stream>>>(wq, wqTh, wqTl, 128, 128);
  k_transw<<<(128*128+255)/256, 256, 0, stream>>>(wk, wkTh, wkTl, 128, 128);
  k_transw<<<(128*128+255)/256, 256, 0, stream>>>(wv, wvTh, wvTl, 128, 128);
  k_transw<<<(512*256+255)/256, 256, 0, stream>>>(g1w, g1wTh, g1wTl, 512, 256);
  k_transw<<<(128*128+255)/256, 256, 0, stream>>>(gc_w, gcwTh, gcwTl, 128, 128);
  k_transw<<<(128*128+255)/256, 256, 0, stream>>>(gc_w + 128*128, gcwTh + 128*128, gcwTl + 128*128, 128, 128);

  const float* Ecur = embed;
  float* curbufs[2] = {cur0, cur1};
  for (int l = 0; l < 2; l++){
    k_norm<<<NN, 64, 0, stream>>>(Ecur, invn, nrm64, Ehi, Elo);
    k_transpose<<<dim3(128,2), 256, 0, stream>>>(Ehi, EhiT);
    k_transpose<<<dim3(128,2), 256, 0, stream>>>(Elo, EloT);
    k_gemm<4,128,false,1><<<256,128,0,stream>>>(Ecur,Ecur,Ecur,Ecur, wqTh, wqTl, bq, QSCALE, nullptr, Qh, nullptr);
    k_gemm<4,128,false,1><<<256,128,0,stream>>>(Ecur,Ecur,Ecur,Ecur, wkTh, wkTl, bk, 1.f, nullptr, Khb, nullptr);
    k_gemm<4,128,false,2><<<256,128,0,stream>>>(Ecur,Ecur,Ecur,Ecur, wvTh, wvTl, bv, 1.f, nullptr, Vh, Vlo);
    k_transpose<<<dim3(128,2), 256, 0, stream>>>(Vh, VhT);
    k_transpose<<<dim3(128,2), 256, 0, stream>>>(Vlo, VloT);
    hipMemsetAsync(zbase, 0, zbytes, stream);
    k_fused<<<512, 256, 0, stream>>>(adjw, invn, Ehi, Elo, EhiT, EloT, Qh, Khb, VhT, VloT,
        Psum, Nsum, Bsum, cntP, cntN, denB, flagCnt, flags);
    k_refine<<<512, 256, 0, stream>>>(Ecur, nrm64, Ehi, Elo, VhT, VloT, flagCnt, flags,
        Psum, Nsum, Bsum, cntP, cntN, denB);
    k_regions<<<4096, 256, 0, stream>>>(Psum, Nsum, Bsum, cntP, cntN, denB);
    k_gemm<16,256,true,0><<<256,128,0,stream>>>(Ecur, Psum, Bsum, Nsum, g1wTh, g1wTl, g1b, 1.f, hbuf, nullptr, nullptr);
    k_fuse<<<NN, 64, 0, stream>>>(Ecur, Psum, Bsum, Nsum, hbuf, g2w, g2b, cntP, cntN, denB, aggb);
    k_gemm<4,128,true,0><<<256,128,0,stream>>>(aggb,aggb,aggb,aggb, gcwTh + l*128*128, gcwTl + l*128*128, gc_b + l*128, 1.f, curbufs[l], nullptr, nullptr);
    Ecur = curbufs[l];
  }
  k_final<<<4096, 256, 0, stream>>>(cur0, cur1, lw, out);
}

// Round 3
// 1367.407 us; speedup vs baseline: 1.2961x; 1.2961x over previous
//
#include <hip/hip_runtime.h>
#include <stdint.h>

#define NN 8192
#define DD 128
#define ALPHA 0.7f
#define BETA 0.3f
#define LAM 0.1f
#define QSCALE 0.08838834764831845f  // 1/sqrt(128)
#define DELTA 3e-5f
#define FLAGCAP 262144

typedef __attribute__((ext_vector_type(8))) short short8;
typedef __attribute__((ext_vector_type(4))) float f32x4;
typedef unsigned short ush;

__device__ __forceinline__ ush f2bf(float f){
  union { float f; unsigned u; } v; v.f = f;
  return (ush)((v.u + 0x7FFFu + ((v.u >> 16) & 1u)) >> 16);
}
__device__ __forceinline__ float bf2f(ush s){
  union { unsigned u; float f; } v; v.u = ((unsigned)s) << 16; return v.f;
}

// ---------------- adjacency -> bitmask ----------------
__global__ void k_pack(const float* __restrict__ adj, unsigned* __restrict__ adjw){
  int i = blockIdx.x, wave = threadIdx.x >> 6, lane = threadIdx.x & 63;
  for (int seg = wave; seg < 128; seg += 4){
    int j = seg*64 + lane;
    unsigned long long bm = __ballot(adj[(size_t)i*NN + j] != 0.0f);
    if (lane == 0)  adjw[i*256 + seg*2]     = (unsigned)bm;
    if (lane == 32) adjw[i*256 + seg*2 + 1] = (unsigned)(bm >> 32);
  }
}

// ---------------- norms + normalized hi/lo split ----------------
__global__ void k_norm(const float* __restrict__ E, double* __restrict__ nrm64,
                       ush* __restrict__ Enh, ush* __restrict__ Enl){
  int i = blockIdx.x, l = threadIdx.x;
  float v0 = E[i*DD + l], v1 = E[i*DD + 64 + l];
  double ss = (double)v0*(double)v0 + (double)v1*(double)v1;
  #pragma unroll
  for (int m = 32; m; m >>= 1) ss += __shfl_xor(ss, m, 64);
  double nr = sqrt(ss); if (nr < 1e-8) nr = 1e-8;
  float inv = (float)(1.0 / nr);
  float n0 = v0*inv, n1 = v1*inv;
  ush h0 = f2bf(n0), h1 = f2bf(n1);
  Enh[i*DD + l] = h0;       Enh[i*DD + 64 + l] = h1;
  Enl[i*DD + l] = f2bf(n0 - bf2f(h0));
  Enl[i*DD + 64 + l] = f2bf(n1 - bf2f(h1));
  if (l == 0) nrm64[i] = nr;
}

// ---------------- fp32 [8192,128] -> hi/lo bf16 transposed [128,8192] ----------------
__global__ void k_transsplit(const float* __restrict__ in, ush* __restrict__ outH,
                             ush* __restrict__ outL){
  __shared__ float t[64][65];
  int r0 = blockIdx.x * 64, c0 = blockIdx.y * 64;
  for (int idx = threadIdx.x; idx < 4096; idx += 256){
    int r = idx >> 6, c = idx & 63;
    t[r][c] = in[(r0 + r)*DD + c0 + c];
  }
  __syncthreads();
  for (int idx = threadIdx.x; idx < 4096; idx += 256){
    int c = idx >> 6, r = idx & 63;
    float v = t[r][c];
    ush h = f2bf(v);
    outH[(size_t)(c0 + c)*NN + r0 + r] = h;
    outL[(size_t)(c0 + c)*NN + r0 + r] = f2bf(v - bf2f(h));
  }
}

// ---------------- fp32 weight transpose+split [K,N] -> hi/lo bf16 [N,K] ----------------
__global__ void k_transw(const float* __restrict__ in, ush* __restrict__ outH,
                         ush* __restrict__ outL, int K, int Nout){
  int idx = blockIdx.x * blockDim.x + threadIdx.x;
  if (idx < K * Nout){
    int k = idx / Nout, n = idx - k*Nout;
    float v = in[idx];
    ush h = f2bf(v);
    outH[n*K + k] = h;
    outL[n*K + k] = f2bf(v - bf2f(h));
  }
}

// ---------------- hi/lo MFMA GEMM: out = act((A@W + b) * scale) ----------------
// OMODE: 0 = fp32 out, 1 = bf16 hi out
template<int KSTEPS, int NOUT, bool RELU, int OMODE>
__global__ void k_gemm(const float* __restrict__ A0, const float* __restrict__ A1,
                       const float* __restrict__ A2, const float* __restrict__ A3,
                       const ush* __restrict__ BtH, const ush* __restrict__ BtL,
                       const float* __restrict__ bias, float scale,
                       float* __restrict__ outF, ush* __restrict__ outH){
  const int K = KSTEPS * 32;
  int lane = threadIdx.x & 63, wave = threadIdx.x >> 6;
  int l15 = lane & 15, quad = lane >> 4;
  int row16 = blockIdx.x * 32 + wave * 16;
  const float* bases[4] = {A0, A1, A2, A3};
  f32x4 acc[NOUT/16];
  #pragma unroll
  for (int nf = 0; nf < NOUT/16; nf++){ f32x4 z = {0.f,0.f,0.f,0.f}; acc[nf] = z; }
  #pragma unroll
  for (int kk = 0; kk < KSTEPS; kk++){
    const float* Ab = bases[kk >> 2];
    int koff = (kk & 3)*32 + quad*8;
    const float* ap = &Ab[(row16 + l15)*DD + koff];
    short8 ah, al;
    #pragma unroll
    for (int j = 0; j < 8; j++){
      float v = ap[j];
      ush h = f2bf(v);
      ah[j] = (short)h; al[j] = (short)f2bf(v - bf2f(h));
    }
    #pragma unroll
    for (int nf = 0; nf < NOUT/16; nf++){
      int bo = (nf*16 + l15)*K + kk*32 + quad*8;
      short8 bh = *(const short8*)&BtH[bo];
      short8 bl = *(const short8*)&BtL[bo];
      acc[nf] = __builtin_amdgcn_mfma_f32_16x16x32_bf16(ah, bh, acc[nf], 0, 0, 0);
      acc[nf] = __builtin_amdgcn_mfma_f32_16x16x32_bf16(al, bh, acc[nf], 0, 0, 0);
      acc[nf] = __builtin_amdgcn_mfma_f32_16x16x32_bf16(ah, bl, acc[nf], 0, 0, 0);
    }
  }
  #pragma unroll
  for (int nf = 0; nf < NOUT/16; nf++){
    int col = nf*16 + l15;
    float b = bias[col];
    #pragma unroll
    for (int r = 0; r < 4; r++){
      int row = row16 + quad*4 + r;
      float v = (acc[nf][r] + b) * scale;
      if (RELU) v = fmaxf(v, 0.f);
      if (OMODE == 0) outF[row*NOUT + col] = v;
      else            outH[row*NOUT + col] = f2bf(v);
    }
  }
}

// ---------------- fused sim/classify/aggregate ----------------
#define BM 64
#define BN 32
#define CSPLIT 4
#define CCHUNK (NN/CSPLIT)
#define NTILES (CCHUNK/BN)
#define RSTRIDE 136   // shorts: row-major sim tiles [32][RSTRIDE] (272B rows, bank-uniform)
#define FSTRIDE 80    // shorts: feature-major [128][2][40] (160B rows, 80B hi/lo sub)
#define MSTRIDE 80    // shorts: masks [16][2][40]

__launch_bounds__(256, 2)
__global__ void k_fused(const unsigned* __restrict__ adjw,
    const ush* __restrict__ Enh, const ush* __restrict__ Enl,
    const ush* __restrict__ Qh,  const ush* __restrict__ Kh,
    const ush* __restrict__ EhiT, const ush* __restrict__ EloT,
    const ush* __restrict__ VhT,  const ush* __restrict__ VloT,
    float* __restrict__ Psum, float* __restrict__ Nsum, float* __restrict__ Bsum,
    float* __restrict__ cntP, float* __restrict__ cntN, float* __restrict__ denB,
    int* __restrict__ flagCnt, float4* __restrict__ flags)
{
  __shared__ __attribute__((aligned(16))) ush sEnh[32*RSTRIDE];
  __shared__ __attribute__((aligned(16))) ush sEnl[32*RSTRIDE];
  __shared__ __attribute__((aligned(16))) ush sKh [32*RSTRIDE];
  __shared__ __attribute__((aligned(16))) ush sE2 [128*FSTRIDE];  // raw E hi/lo feature-major
  __shared__ __attribute__((aligned(16))) ush sV2 [128*FSTRIDE];  // V hi/lo feature-major
  __shared__ __attribute__((aligned(16))) ush sM  [4][16*MSTRIDE];

  int tid = threadIdx.x, lane = tid & 63, wave = tid >> 6;
  int l15 = lane & 15, quad = lane >> 4;
  int rowblk = blockIdx.x >> 2, split = blockIdx.x & 3;
  int row0 = rowblk * BM + wave * 16;
  int col0 = split * CCHUNK;

  // wave row-fragments (used as MFMA B-operand; A/B lane maps are identical m<->n)
  short8 bEnh[4], bEnl[4], bQ[4];
  #pragma unroll
  for (int kf = 0; kf < 4; kf++){
    int go = (row0 + l15)*DD + kf*32 + quad*8;
    bEnh[kf] = *(const short8*)&Enh[go];
    bEnl[kf] = *(const short8*)&Enl[go];
    bQ  [kf] = *(const short8*)&Qh [go];
  }

  f32x4 accP[8], accN[8], accB[8];
  #pragma unroll
  for (int nf = 0; nf < 8; nf++){ f32x4 z = {0.f,0.f,0.f,0.f}; accP[nf]=z; accN[nf]=z; accB[nf]=z; }
  float cpL = 0.f, cnL = 0.f, dbL = 0.f;

  // feature-major prefetch indices
  int f0 = tid >> 2,        n0 = (tid & 3)*8;
  int f1 = (tid+256) >> 2,  n1 = ((tid+256) & 3)*8;
  uint4 pEh0, pEh1, pEl0, pEl1, pVh0, pVh1, pVl0, pVl1;
  {
    size_t g0 = (size_t)f0*NN + col0 + n0, g1 = (size_t)f1*NN + col0 + n1;
    pEh0 = *(const uint4*)&EhiT[g0]; pEh1 = *(const uint4*)&EhiT[g1];
    pEl0 = *(const uint4*)&EloT[g0]; pEl1 = *(const uint4*)&EloT[g1];
    pVh0 = *(const uint4*)&VhT [g0]; pVh1 = *(const uint4*)&VhT [g1];
    pVl0 = *(const uint4*)&VloT[g0]; pVl1 = *(const uint4*)&VloT[g1];
  }
  // row-major staging indices
  int rr0 = tid >> 4,       ro0 = (tid & 15)*8;
  int rr1 = (tid+256) >> 4, ro1 = ((tid+256) & 15)*8;

  for (int t = 0; t < NTILES; t++){
    int c0 = col0 + t*BN;
    __syncthreads();
    // store prefetched feature-major tiles
    *(uint4*)&sE2[f0*FSTRIDE + n0]      = pEh0;  *(uint4*)&sE2[f1*FSTRIDE + n1]      = pEh1;
    *(uint4*)&sE2[f0*FSTRIDE + 40 + n0] = pEl0;  *(uint4*)&sE2[f1*FSTRIDE + 40 + n1] = pEl1;
    *(uint4*)&sV2[f0*FSTRIDE + n0]      = pVh0;  *(uint4*)&sV2[f1*FSTRIDE + n1]      = pVh1;
    *(uint4*)&sV2[f0*FSTRIDE + 40 + n0] = pVl0;  *(uint4*)&sV2[f1*FSTRIDE + 40 + n1] = pVl1;
    // direct row-major staging (normalized E hi/lo + K)
    {
      uint4 a0 = *(const uint4*)&Enh[(c0 + rr0)*DD + ro0];
      uint4 a1 = *(const uint4*)&Enh[(c0 + rr1)*DD + ro1];
      uint4 b0 = *(const uint4*)&Enl[(c0 + rr0)*DD + ro0];
      uint4 b1 = *(const uint4*)&Enl[(c0 + rr1)*DD + ro1];
      uint4 k0 = *(const uint4*)&Kh [(c0 + rr0)*DD + ro0];
      uint4 k1 = *(const uint4*)&Kh [(c0 + rr1)*DD + ro1];
      *(uint4*)&sEnh[rr0*RSTRIDE + ro0] = a0;  *(uint4*)&sEnh[rr1*RSTRIDE + ro1] = a1;
      *(uint4*)&sEnl[rr0*RSTRIDE + ro0] = b0;  *(uint4*)&sEnl[rr1*RSTRIDE + ro1] = b1;
      *(uint4*)&sKh [rr0*RSTRIDE + ro0] = k0;  *(uint4*)&sKh [rr1*RSTRIDE + ro1] = k1;
    }
    __syncthreads();
    // prefetch next tile's feature-major (overlaps this tile's compute)
    if (t + 1 < NTILES){
      int c1 = c0 + BN;
      size_t g0 = (size_t)f0*NN + c1 + n0, g1 = (size_t)f1*NN + c1 + n1;
      pEh0 = *(const uint4*)&EhiT[g0]; pEh1 = *(const uint4*)&EhiT[g1];
      pEl0 = *(const uint4*)&EloT[g0]; pEl1 = *(const uint4*)&EloT[g1];
      pVh0 = *(const uint4*)&VhT [g0]; pVh1 = *(const uint4*)&VhT [g1];
      pVl0 = *(const uint4*)&VloT[g0]; pVl1 = *(const uint4*)&VloT[g1];
    }
    // adjacency word for this lane's row (one 32-col word covers the tile)
    unsigned aw = adjw[(row0 + l15)*256 + (c0 >> 5)];

    // simT[f]: D[m=col-in-16f][n=row] = sum_d En[col][d] * En[row][d]  (hi/lo x3)
    // svT [f]: D[m=col][n=row] = sum_d K[col][d] * Q[row][d]
    f32x4 simT[2], svT[2];
    { f32x4 z = {0.f,0.f,0.f,0.f}; simT[0]=z; simT[1]=z; svT[0]=z; svT[1]=z; }
    #pragma unroll
    for (int f = 0; f < 2; f++){
      #pragma unroll
      for (int kf = 0; kf < 4; kf++){
        int la = (f*16 + l15)*RSTRIDE + kf*32 + quad*8;
        short8 ch = *(const short8*)&sEnh[la];
        short8 cl = *(const short8*)&sEnl[la];
        short8 ck = *(const short8*)&sKh [la];
        simT[f] = __builtin_amdgcn_mfma_f32_16x16x32_bf16(ch, bEnh[kf], simT[f],0,0,0);
        simT[f] = __builtin_amdgcn_mfma_f32_16x16x32_bf16(cl, bEnh[kf], simT[f],0,0,0);
        simT[f] = __builtin_amdgcn_mfma_f32_16x16x32_bf16(ch, bEnl[kf], simT[f],0,0,0);
        svT [f] = __builtin_amdgcn_mfma_f32_16x16x32_bf16(ck, bQ  [kf], svT [f],0,0,0);
      }
    }
    // classify: lane holds (row = row0+l15, cols = f*16 + quad*4 + r)
    ushort4 ehv[2], elv[2];
    unsigned flagb = 0;
    #pragma unroll
    for (int f = 0; f < 2; f++){
      ush vp[4], vn2[4], veh[4], vel[4];
      #pragma unroll
      for (int r = 0; r < 4; r++){
        int cbit = f*16 + quad*4 + r;
        bool nbr = (aw >> cbit) & 1u;
        float c = simT[f][r], s = svT[f][r];
        bool pos = nbr && (c >= ALPHA);
        bool neg = nbr && (c <= BETA);
        bool bnd = nbr && !pos && !neg;
        float e = bnd ? __expf(s) : 0.f;
        ush eh = f2bf(e);
        vp[r]  = pos ? (ush)0x3F80 : (ush)0;
        vn2[r] = neg ? (ush)0x3F80 : (ush)0;
        veh[r] = eh;
        vel[r] = f2bf(e - bf2f(eh));
        cpL += pos ? 1.f : 0.f;
        cnL += neg ? 1.f : 0.f;
        dbL += e;
        if (nbr && (fabsf(c - ALPHA) < DELTA || fabsf(c - BETA) < DELTA))
          flagb |= 1u << (f*4 + r);
      }
      int mb = l15*MSTRIDE + f*16 + quad*4;
      *(ushort4*)&sM[wave][mb]      = make_ushort4(vp[0],vp[1],vp[2],vp[3]);
      *(ushort4*)&sM[wave][mb + 40] = make_ushort4(vn2[0],vn2[1],vn2[2],vn2[3]);
      ehv[f] = make_ushort4(veh[0],veh[1],veh[2],veh[3]);
      elv[f] = make_ushort4(vel[0],vel[1],vel[2],vel[3]);
    }
    // rare boundary-flag export
    if (__ballot(flagb != 0)){
      #pragma unroll
      for (int f = 0; f < 2; f++){
        #pragma unroll
        for (int r = 0; r < 4; r++){
          bool fl = (flagb >> (f*4 + r)) & 1u;
          unsigned long long bm = __ballot(fl);
          if (bm){
            int leader = __ffsll((long long)bm) - 1;
            int base = 0;
            if (lane == leader) base = atomicAdd(flagCnt, __popcll(bm));
            base = __shfl(base, leader, 64);
            if (fl){
              int id = base + __popcll(bm & ((1ull << lane) - 1ull));
              if (id < FLAGCAP){
                float4 rec;
                rec.x = __int_as_float(row0 + l15);
                rec.y = __int_as_float(c0 + f*16 + quad*4 + r);
                rec.z = simT[f][r]; rec.w = svT[f][r];
                flags[id] = rec;
              }
            }
          }
        }
      }
    }
    // phase A: P/N accumulation (mask A-frag: row=l15, k=cols)
    {
      short8 mPos = *(const short8*)&sM[wave][l15*MSTRIDE + quad*8];
      short8 mNeg = *(const short8*)&sM[wave][l15*MSTRIDE + 40 + quad*8];
      #pragma unroll
      for (int nf = 0; nf < 8; nf++){
        int so = (nf*16 + l15)*FSTRIDE + quad*8;
        short8 eth = *(const short8*)&sE2[so];
        short8 etl = *(const short8*)&sE2[so + 40];
        accP[nf] = __builtin_amdgcn_mfma_f32_16x16x32_bf16(mPos, eth, accP[nf],0,0,0);
        accP[nf] = __builtin_amdgcn_mfma_f32_16x16x32_bf16(mPos, etl, accP[nf],0,0,0);
        accN[nf] = __builtin_amdgcn_mfma_f32_16x16x32_bf16(mNeg, eth, accN[nf],0,0,0);
        accN[nf] = __builtin_amdgcn_mfma_f32_16x16x32_bf16(mNeg, etl, accN[nf],0,0,0);
      }
    }
    // phase B: overwrite masks with e hi/lo (same-wave DS is in-order), accumulate B
    {
      int mb0 = l15*MSTRIDE + quad*4;
      *(ushort4*)&sM[wave][mb0]           = ehv[0];
      *(ushort4*)&sM[wave][mb0 + 16]      = ehv[1];
      *(ushort4*)&sM[wave][mb0 + 40]      = elv[0];
      *(ushort4*)&sM[wave][mb0 + 40 + 16] = elv[1];
      short8 mEh = *(const short8*)&sM[wave][l15*MSTRIDE + quad*8];
      short8 mEl = *(const short8*)&sM[wave][l15*MSTRIDE + 40 + quad*8];
      #pragma unroll
      for (int nf = 0; nf < 8; nf++){
        int so = (nf*16 + l15)*FSTRIDE + quad*8;
        short8 vth = *(const short8*)&sV2[so];
        short8 vtl = *(const short8*)&sV2[so + 40];
        accB[nf] = __builtin_amdgcn_mfma_f32_16x16x32_bf16(mEh, vth, accB[nf],0,0,0);
        accB[nf] = __builtin_amdgcn_mfma_f32_16x16x32_bf16(mEl, vth, accB[nf],0,0,0);
        accB[nf] = __builtin_amdgcn_mfma_f32_16x16x32_bf16(mEh, vtl, accB[nf],0,0,0);
      }
    }
  }
  // writeback: D[m=row-in-16][n=feat-in-16]
  #pragma unroll
  for (int nf = 0; nf < 8; nf++){
    int col = nf*16 + l15;
    #pragma unroll
    for (int r = 0; r < 4; r++){
      int row = row0 + quad*4 + r;
      atomicAdd(&Psum[row*DD + col], accP[nf][r]);
      atomicAdd(&Nsum[row*DD + col], accN[nf][r]);
      atomicAdd(&Bsum[row*DD + col], accB[nf][r]);
    }
  }
  // counts: reduce across quads (lanes sharing l15)
  cpL += __shfl_xor(cpL, 16, 64); cpL += __shfl_xor(cpL, 32, 64);
  cnL += __shfl_xor(cnL, 16, 64); cnL += __shfl_xor(cnL, 32, 64);
  dbL += __shfl_xor(dbL, 16, 64); dbL += __shfl_xor(dbL, 32, 64);
  if (quad == 0){
    atomicAdd(&cntP[row0 + l15], cpL);
    atomicAdd(&cntN[row0 + l15], cnL);
    atomicAdd(&denB[row0 + l15], dbL);
  }
}

// ---------------- fp64 boundary refinement + sparse fixup ----------------
__global__ void k_refine(const float* __restrict__ E, const double* __restrict__ nrm64,
    const ush* __restrict__ EhiT, const ush* __restrict__ EloT,
    const ush* __restrict__ VhT,  const ush* __restrict__ VloT,
    const int* __restrict__ flagCnt, const float4* __restrict__ flags,
    float* __restrict__ Psum, float* __restrict__ Nsum, float* __restrict__ Bsum,
    float* __restrict__ cntP, float* __restrict__ cntN, float* __restrict__ denB)
{
  int cnt = *flagCnt; if (cnt > FLAGCAP) cnt = FLAGCAP;
  int lane = threadIdx.x & 63;
  int gw = (blockIdx.x * blockDim.x + threadIdx.x) >> 6;
  int nw = (gridDim.x * blockDim.x) >> 6;
  for (int idx = gw; idx < cnt; idx += nw){
    float4 rec = flags[idx];
    int i = __float_as_int(rec.x), j = __float_as_int(rec.y);
    float c = rec.z, s = rec.w;
    float ei0 = E[i*DD + lane], ei1 = E[i*DD + 64 + lane];
    float ej0 = E[j*DD + lane], ej1 = E[j*DD + 64 + lane];
    double d = (double)ei0*(double)ej0 + (double)ei1*(double)ej1;
    #pragma unroll
    for (int m = 32; m; m >>= 1) d += __shfl_xor(d, m, 64);
    double se = d / (nrm64[i]*nrm64[j]);
    int ce = (se >= (double)ALPHA) ? 0 : ((se <= (double)BETA) ? 1 : 2);
    int cc = (c >= ALPHA) ? 0 : ((c <= BETA) ? 1 : 2);
    if (ce == cc) continue;
    float e = __expf(s);
    float ehf = bf2f(f2bf(e));
    float elf = bf2f(f2bf(e - ehf));
    #pragma unroll
    for (int h = 0; h < 2; h++){
      int dd2 = lane + h*64;
      float ev = bf2f(EhiT[(size_t)dd2*NN + j]) + bf2f(EloT[(size_t)dd2*NN + j]);
      float vh = bf2f(VhT[(size_t)dd2*NN + j]);
      float vl = bf2f(VloT[(size_t)dd2*NN + j]);
      float bv = ehf*vh + elf*vh + ehf*vl;
      float* subA = (cc==0) ? Psum : (cc==1) ? Nsum : Bsum;
      atomicAdd(&subA[i*DD + dd2], (cc==2) ? -bv : -ev);
      float* addA = (ce==0) ? Psum : (ce==1) ? Nsum : Bsum;
      atomicAdd(&addA[i*DD + dd2], (ce==2) ?  bv :  ev);
    }
    if (lane == 0){
      float* subC = (cc==0) ? cntP : (cc==1) ? cntN : denB;
      atomicAdd(&subC[i], (cc==2) ? -e : -1.f);
      float* addC = (ce==0) ? cntP : (ce==1) ? cntN : denB;
      atomicAdd(&addC[i], (ce==2) ?  e :  1.f);
    }
  }
}

// ---------------- divide sums into region embeddings (in place) ----------------
__global__ void k_regions(float* __restrict__ P, float* __restrict__ Nn, float* __restrict__ B,
    const float* __restrict__ cntP, const float* __restrict__ cntN, const float* __restrict__ denB){
  int idx = blockIdx.x*blockDim.x + threadIdx.x;
  int i = idx >> 7;
  P[idx]  = P[idx] / fmaxf(cntP[i], 1.f);
  Nn[idx] = LAM * Nn[idx] / fmaxf(cntN[i], 1.f);
  float dn = denB[i];
  B[idx]  = (dn > 0.5f) ? B[idx]/dn : 0.f;
}

// ---------------- gate + fuse ----------------
__global__ void k_fuse(const float* __restrict__ E, const float* __restrict__ P,
    const float* __restrict__ B, const float* __restrict__ Nn,
    const float* __restrict__ h, const float* __restrict__ g2w, const float* __restrict__ g2b,
    const float* __restrict__ cntP, const float* __restrict__ cntN, const float* __restrict__ denB,
    float* __restrict__ agg){
  int i = blockIdx.x, lane = threadIdx.x;
  float l0=0,l1=0,l2=0,l3=0;
  #pragma unroll
  for (int kk = 0; kk < 4; kk++){
    int k = lane + kk*64;
    float hv = h[i*256 + k];
    l0 = fmaf(hv, g2w[k*4+0], l0);
    l1 = fmaf(hv, g2w[k*4+1], l1);
    l2 = fmaf(hv, g2w[k*4+2], l2);
    l3 = fmaf(hv, g2w[k*4+3], l3);
  }
  #pragma unroll
  for (int m = 1; m < 64; m <<= 1){
    l0 += __shfl_xor(l0, m, 64); l1 += __shfl_xor(l1, m, 64);
    l2 += __shfl_xor(l2, m, 64); l3 += __shfl_xor(l3, m, 64);
  }
  l0 += g2b[0]; l1 += g2b[1]; l2 += g2b[2]; l3 += g2b[3];
  float mx = fmaxf(fmaxf(l0,l1), fmaxf(l2,l3));
  float e0 = __expf(l0-mx), e1 = __expf(l1-mx), e2 = __expf(l2-mx), e3 = __expf(l3-mx);
  float inv = 1.f/(e0+e1+e2+e3);
  float g0 = e0*inv, g1 = e1*inv, g2v = e2*inv, g3 = e3*inv;
  bool any = (cntP[i] + cntN[i] > 0.5f) || (denB[i] > 0.5f);
  #pragma unroll
  for (int hh = 0; hh < 2; hh++){
    int idx = i*DD + lane + hh*64;
    float v = any ? (g0*E[idx] + g1*P[idx] + g2v*B[idx] + g3*Nn[idx]) : E[idx];
    agg[idx] = v;
  }
}

// ---------------- final layer-weighted combine ----------------
__global__ void k_final(const float* __restrict__ c0, const float* __restrict__ c1,
                        const float* __restrict__ lwv, float* __restrict__ out){
  int idx = blockIdx.x*blockDim.x + threadIdx.x;
  float w0 = lwv[0], w1 = lwv[1];
  float mx = fmaxf(w0, w1);
  float e0 = __expf(w0-mx), e1 = __expf(w1-mx);
  float inv = 1.f/(e0+e1);
  out[idx] = (e0*inv)*c0[idx] + (e1*inv)*c1[idx];
}

extern "C" void kernel_launch(void* const* d_in, const int* in_sizes, int n_in,
                              void* d_out, int out_size, void* d_ws, size_t ws_size,
                              hipStream_t stream){
  const float* adj   = (const float*)d_in[0];
  const float* embed = (const float*)d_in[1];
  const float* gc_w  = (const float*)d_in[2];
  const float* gc_b  = (const float*)d_in[3];
  const float* wq = (const float*)d_in[4];
  const float* bq = (const float*)d_in[5];
  const float* wk = (const float*)d_in[6];
  const float* bk = (const float*)d_in[7];
  const float* wv = (const float*)d_in[8];
  const float* bv = (const float*)d_in[9];
  const float* g1w = (const float*)d_in[10];
  const float* g1b = (const float*)d_in[11];
  const float* g2w = (const float*)d_in[12];
  const float* g2b = (const float*)d_in[13];
  const float* lw  = (const float*)d_in[14];
  float* out = (float*)d_out;

  char* p = (char*)d_ws;
  auto alloc = [&](size_t bytes)->void*{ void* r = (void*)p; p += (bytes + 255) & ~(size_t)255; return r; };
  ush* wqTh  = (ush*)alloc(128*128*2); ush* wqTl  = (ush*)alloc(128*128*2);
  ush* wkTh  = (ush*)alloc(128*128*2); ush* wkTl  = (ush*)alloc(128*128*2);
  ush* wvTh  = (ush*)alloc(128*128*2); ush* wvTl  = (ush*)alloc(128*128*2);
  ush* g1wTh = (ush*)alloc(512*256*2); ush* g1wTl = (ush*)alloc(512*256*2);
  ush* gcwTh = (ush*)alloc(2*128*128*2); ush* gcwTl = (ush*)alloc(2*128*128*2);
  unsigned* adjw = (unsigned*)alloc((size_t)NN*256*4);
  double* nrm64 = (double*)alloc(NN*8);
  ush* Enh  = (ush*)alloc((size_t)NN*DD*2);
  ush* Enl  = (ush*)alloc((size_t)NN*DD*2);
  ush* EhiT = (ush*)alloc((size_t)NN*DD*2);
  ush* EloT = (ush*)alloc((size_t)NN*DD*2);
  ush* Qh   = (ush*)alloc((size_t)NN*DD*2);
  ush* Khb  = (ush*)alloc((size_t)NN*DD*2);
  ush* VhT  = (ush*)alloc((size_t)NN*DD*2);
  ush* VloT = (ush*)alloc((size_t)NN*DD*2);
  float* Vf = (float*)alloc((size_t)NN*DD*4);
  char* zbase = p;
  float* Psum = (float*)alloc((size_t)NN*DD*4);
  float* Nsum = (float*)alloc((size_t)NN*DD*4);
  float* Bsum = (float*)alloc((size_t)NN*DD*4);
  float* cntP = (float*)alloc(NN*4);
  float* cntN = (float*)alloc(NN*4);
  float* denB = (float*)alloc(NN*4);
  int*   flagCnt = (int*)alloc(256);
  size_t zbytes = (size_t)(p - zbase);
  float4* flags = (float4*)alloc((size_t)FLAGCAP*16);
  float* hbuf = (float*)alloc((size_t)NN*256*4);
  float* aggb = (float*)alloc((size_t)NN*DD*4);
  float* cur0 = (float*)alloc((size_t)NN*DD*4);
  float* cur1 = (float*)alloc((size_t)NN*DD*4);

  // one-time prep (per call; inputs restored each replay)
  k_pack<<<NN, 256, 0, stream>>>(adj, adjw);
  k_transw<<<(128*128+255)/256, 256, 0, stream>>>(wq, wqTh, wqTl, 128, 128);
  k_transw<<<(128*128+255)/256, 256, 0, stream>>>(wk, wkTh, wkTl, 128, 128);
  k_transw<<<(128*128+255)/256, 256, 0, stream>>>(wv, wvTh, wvTl, 128, 128);
  k_transw<<<(512*256+255)/256, 256, 0, stream>>>(g1w, g1wTh, g1wTl, 512, 256);
  k_transw<<<(128*128+255)/256, 256, 0, stream>>>(gc_w, gcwTh, gcwTl, 128, 128);
  k_transw<<<(128*128+255)/256, 256, 0, stream>>>(gc_w + 128*128, gcwTh + 128*128, gcwTl + 128*128, 128, 128);

  const float* Ecur = embed;
  float* curbufs[2] = {cur0, cur1};
  for (int l = 0; l < 2; l++){
    k_norm<<<NN, 64, 0, stream>>>(Ecur, nrm64, Enh, Enl);
    k_transsplit<<<dim3(128,2), 256, 0, stream>>>(Ecur, EhiT, EloT);
    k_gemm<4,128,false,1><<<256,128,0,stream>>>(Ecur,Ecur,Ecur,Ecur, wqTh, wqTl, bq, QSCALE, nullptr, Qh);
    k_gemm<4,128,false,1><<<256,128,0,stream>>>(Ecur,Ecur,Ecur,Ecur, wkTh, wkTl, bk, 1.f, nullptr, Khb);
    k_gemm<4,128,false,0><<<256,128,0,stream>>>(Ecur,Ecur,Ecur,Ecur, wvTh, wvTl, bv, 1.f, Vf, nullptr);
    k_transsplit<<<dim3(128,2), 256, 0, stream>>>(Vf, VhT, VloT);
    hipMemsetAsync(zbase, 0, zbytes, stream);
    k_fused<<<512, 256, 0, stream>>>(adjw, Enh, Enl, Qh, Khb, EhiT, EloT, VhT, VloT,
        Psum, Nsum, Bsum, cntP, cntN, denB, flagCnt, flags);
    k_refine<<<512, 256, 0, stream>>>(Ecur, nrm64, EhiT, EloT, VhT, VloT, flagCnt, flags,
        Psum, Nsum, Bsum, cntP, cntN, denB);
    k_regions<<<4096, 256, 0, stream>>>(Psum, Nsum, Bsum, cntP, cntN, denB);
    k_gemm<16,256,true,0><<<256,128,0,stream>>>(Ecur, Psum, Bsum, Nsum, g1wTh, g1wTl, g1b, 1.f, hbuf, nullptr);
    k_fuse<<<NN, 64, 0, stream>>>(Ecur, Psum, Bsum, Nsum, hbuf, g2w, g2b, cntP, cntN, denB, aggb);
    k_gemm<4,128,true,0><<<256,128,0,stream>>>(aggb,aggb,aggb,aggb, gcwTh + l*128*128, gcwTl + l*128*128, gc_b + l*128, 1.f, curbufs[l], nullptr);
    Ecur = curbufs[l];
  }
  k_final<<<4096, 256, 0, stream>>>(cur0, cur1, lw, out);
}